// Round 15
// baseline (403.422 us; speedup 1.0000x reference)
//
#include <hip/hip_runtime.h>
#include <hip/hip_fp16.h>
#include <cstdint>
#include <cstddef>

typedef _Float16 f16x8 __attribute__((ext_vector_type(8)));
typedef _Float16 f16x4 __attribute__((ext_vector_type(4)));
typedef float    f32x4 __attribute__((ext_vector_type(4)));

// ---------------------------------------------------------------------------
// fake-quant with fractional bit-width interpolation (matches jax reference)
// ---------------------------------------------------------------------------
__device__ __forceinline__ float quant_interp(float v, float alpha) {
    float a    = fmaxf(alpha, 1.0f);
    float blo  = floorf(a);
    float frac = a - blo;
    float slo  = exp2f(blo) - 1.0f;
    float shi  = 2.0f * slo + 1.0f;
    float rslo = __builtin_amdgcn_rcpf(slo);
    float rshi = __builtin_amdgcn_rcpf(shi);
    float c    = fminf(fmaxf(v, -1.0f), 1.0f);
    float qlo  = rintf(c * slo) * rslo;
    float qhi  = rintf(c * shi) * rshi;
    return (1.0f - frac) * qlo + frac * qhi;
}

// ---------------------------------------------------------------------------
// column mean of alpha_a [OUT][IN] -> a_feat [IN], deterministic two-pass
// ---------------------------------------------------------------------------
__global__ void colsum_partial_kernel(const float* __restrict__ aA,
                                      float* __restrict__ partial,
                                      int IN, int rows_per) {
    int col = blockIdx.x * blockDim.x + threadIdx.x;
    size_t r0 = (size_t)blockIdx.y * rows_per;
    float s = 0.f;
    for (int r = 0; r < rows_per; ++r)
        s += aA[(r0 + r) * (size_t)IN + col];
    partial[(size_t)blockIdx.y * IN + col] = s;
}

__global__ void colsum_final_kernel(const float* __restrict__ partial,
                                    float* __restrict__ afeat,
                                    int IN, int nchunk, float inv) {
    int col = blockIdx.x * blockDim.x + threadIdx.x;
    float s = 0.f;
    for (int c = 0; c < nchunk; ++c)
        s += partial[(size_t)c * IN + col];
    afeat[col] = s * inv;
}

// ---------------------------------------------------------------------------
// fused quantize (ONE launch): x then w, 32B loads / 16B store per iteration
// ---------------------------------------------------------------------------
__global__ void quant_xw8_kernel(const float* __restrict__ x,
                                 const float* __restrict__ afeat,
                                 f16x8* __restrict__ qx,
                                 const float* __restrict__ w,
                                 const float* __restrict__ aw,
                                 f16x8* __restrict__ qw,
                                 int IN, size_t nx8, size_t ntot8) {
    size_t i = (size_t)blockIdx.x * blockDim.x + threadIdx.x;
    size_t stride = (size_t)gridDim.x * blockDim.x;
    for (; i < ntot8; i += stride) {
        if (i < nx8) {
            size_t e = i * 8;
            int col = (int)(e % (size_t)IN);
            f32x4 x0 = *(const f32x4*)(x + e);
            f32x4 x1 = *(const f32x4*)(x + e + 4);
            f32x4 a0 = *(const f32x4*)(afeat + col);
            f32x4 a1 = *(const f32x4*)(afeat + col + 4);
            f16x8 o;
            #pragma unroll
            for (int j = 0; j < 4; ++j) o[j]     = (_Float16)quant_interp(x0[j], a0[j]);
            #pragma unroll
            for (int j = 0; j < 4; ++j) o[4 + j] = (_Float16)quant_interp(x1[j], a1[j]);
            qx[i] = o;
        } else {
            size_t k = (i - nx8) * 8;
            f32x4 w0 = *(const f32x4*)(w + k);
            f32x4 w1 = *(const f32x4*)(w + k + 4);
            f32x4 a0 = *(const f32x4*)(aw + k);
            f32x4 a1 = *(const f32x4*)(aw + k + 4);
            f16x8 o;
            #pragma unroll
            for (int j = 0; j < 4; ++j) o[j]     = (_Float16)quant_interp(w0[j], a0[j]);
            #pragma unroll
            for (int j = 0; j < 4; ++j) o[4 + j] = (_Float16)quant_interp(w1[j], a1[j]);
            qw[i - nx8] = o;
        }
    }
}

// ---------------------------------------------------------------------------
// 256x256 NT GEMM, fp16 in / fp32 out — depth-pipelined 4-buffer BK=32.
//   R13/R14 NaN root cause: STAGE32 dest used p*16384; each p-half is 128
//   rows x 64B = 8192 bytes -> p=1 wrote 8KB past its buffer, clobbering the
//   adjacent operand/tile buffers. FIXED: p*8192 (dest byte = p*8192+tid*16
//   -> row = p*128 + (tid>>2), matching the source row; swizzle audit: phys
//   slot tid&3 holds global slot (tid&3)^(row&3); read phys s^(row&3) = s).
//   Schedule (re-audited, no other defect):
//   Per K-tile t (bufs: read t&3, pre-read (t+1)&3, landing (t+2)&3,
//   writing (t+3)&3 — pairwise distinct):
//     af[8]  <- ds_read buf[t][A]                  (published 2 bars ago)
//     bfN[4] <- pre-read B(t+1) from buf[t+1][B]   (published 1 bar ago)
//     stage tile t+3 -> buf[t+3]                   (4 gload_lds)
//     32 MFMA on af x bfC (bfC pre-read LAST tile: zero lgkm wait at start)
//     vmcnt(4) [drains stage(t+2)]; lgkmcnt(0) [publication fence, AFTER
//     MFMAs -- not the pre-MFMA lockstep drain]; s_barrier. ONE barrier/tile.
//   buf[t&3] rewritten earliest at t+1, one barrier after all waves' reads
//   retired. Tail (t >= nkt-3): stages skip -> gate 0.
// ---------------------------------------------------------------------------
__device__ __forceinline__ void gload_lds16(const void* g, void* l) {
    __builtin_amdgcn_global_load_lds(
        (const __attribute__((address_space(1))) void*)g,
        (__attribute__((address_space(3))) void*)l, 16, 0, 0);
}

__device__ __forceinline__ f16x8 lds_frag32(const _Float16* buf, int row, int hi) {
    const int sl = hi ^ (row & 3);
    return *(const f16x8*)((const char*)buf + row * 64 + sl * 16);
}

#define GATE(N)  asm volatile("s_waitcnt vmcnt(" N ")" ::: "memory")
#define LGKM0()  asm volatile("s_waitcnt lgkmcnt(0)" ::: "memory")
#define BAR()    asm volatile("s_barrier" ::: "memory")

#define READ_BN(T, DST)                                                      \
    if ((T) < nkt) {                                                         \
        const _Float16* Bn = &lds[(T) & 3][1][0];                            \
        _Pragma("unroll")                                                    \
        for (int nf = 0; nf < 4; ++nf)                                       \
            DST[nf] = lds_frag32(Bn, (nf >> 1) * 128 + wn * 32 +             \
                                     (nf & 1) * 16 + r15, hi);               \
    }

#define BODY(T, BFC, BFN)                                                    \
  {                                                                          \
    const _Float16* Ab = &lds[(T) & 3][0][0];                                \
    f16x8 af[8];                                                             \
    _Pragma("unroll")                                                        \
    for (int mf = 0; mf < 8; ++mf)                                           \
        af[mf] = lds_frag32(Ab, wm * 128 + mf * 16 + r15, hi);               \
    READ_BN((T) + 1, BFN);                                                   \
    STAGE32((T) + 3, 0); STAGE32((T) + 3, 1);                                \
    __builtin_amdgcn_s_setprio(1);                                           \
    _Pragma("unroll")                                                        \
    for (int mf = 0; mf < 8; ++mf)                                           \
        _Pragma("unroll")                                                    \
        for (int nf = 0; nf < 4; ++nf)                                       \
            acc[mf][nf] = __builtin_amdgcn_mfma_f32_16x16x32_f16(            \
                af[mf], BFC[nf], acc[mf][nf], 0, 0, 0);                      \
    __builtin_amdgcn_s_setprio(0);                                           \
    if ((T) < nkt - 3) { GATE("4"); } else { GATE("0"); }                    \
    LGKM0(); BAR();                                                          \
  }

__global__ __launch_bounds__(512, 2) void gemm_p4_kernel(
    const _Float16* __restrict__ A,   // [M][K] qx
    const _Float16* __restrict__ B,   // [N][K] qw
    const float* __restrict__ bias,   // [N]
    float* __restrict__ C,            // [M][N]
    int M, int N, int K)
{
    constexpr int BK = 32;
    __shared__ _Float16 lds[4][2][256 * BK];   // 4 bufs x {A,B} x 16KB = 128K

    const int tid  = (int)threadIdx.x;
    const int lane = tid & 63;
    const int wave = tid >> 6;
    const int wm   = wave >> 2;    // 0..1  (M half: rows wm*128..+127)
    const int wn   = wave & 3;     // 0..3
    const int r15  = lane & 15;
    const int hi   = lane >> 4;

    const int nbx = N >> 8;
    const int nwg = (M >> 8) * nbx;
    const int bid = (int)blockIdx.x;
    const int swz = (nwg & 7) ? bid : ((bid & 7) * (nwg >> 3) + (bid >> 3));
    const size_t bm0 = (size_t)(swz / nbx) << 8;
    const size_t bn0 = (size_t)(swz % nbx) << 8;

    const int nkt = K / BK;
    const _Float16* Agb = A + bm0 * K;
    const _Float16* Bgb = B + bn0 * K;

    // stage one operand of a BK=32 tile (256 rows x 32 halfs = 16KB):
    // 2 gload_lds per thread; linear LDS dest, source slot pre-XORed.
    // Per p-half: 128 rows x 64B = 8192 B (dest row = p*128 + (tid>>2)).
    auto STAGE32 = [&](int tile, int ab) {
        if (tile >= nkt) return;
        const _Float16* g = (ab == 0 ? Agb : Bgb) + (size_t)tile * BK;
        char* lb = (char*)&lds[tile & 3][ab][0];
        #pragma unroll
        for (int p = 0; p < 2; ++p) {
            const int row = p * 128 + (tid >> 2);
            const int sg  = (tid & 3) ^ (row & 3);
            gload_lds16(g + (size_t)row * K + sg * 8,
                        lb + p * 8192 + (wave << 10));
        }
    };

    f32x4 acc[8][4] = {};
    f16x8 bfC[4], bfN[4];

    // prologue: stage tiles 0,1 (8 loads); full drain + publish; pre-read
    // B(0); stage tile 2 (queue=4 = steady invariant); fence; publish.
    STAGE32(0, 0); STAGE32(0, 1); STAGE32(1, 0); STAGE32(1, 1);
    GATE("0"); BAR();
    READ_BN(0, bfC);
    STAGE32(2, 0); STAGE32(2, 1);
    LGKM0(); BAR();

    for (int t = 0; t < nkt; t += 2) {
        BODY(t,     bfC, bfN);
        BODY(t + 1, bfN, bfC);
    }

    // epilogue: C/D layout col = lane&15, row = (lane>>4)*4 + reg
    #pragma unroll
    for (int nf = 0; nf < 4; ++nf) {
        const size_t col = bn0 + (size_t)((nf >> 1) * 128 + wn * 32 + (nf & 1) * 16 + r15);
        const float bv = bias[col];
        #pragma unroll
        for (int mf = 0; mf < 8; ++mf) {
            const size_t row0 = bm0 + (size_t)(wm * 128 + mf * 16 + hi * 4);
            #pragma unroll
            for (int r = 0; r < 4; ++r)
                C[(row0 + r) * N + col] = acc[mf][nf][r] + bv;
        }
    }
}

// ---------------------------------------------------------------------------
extern "C" void kernel_launch(void* const* d_in, const int* in_sizes, int n_in,
                              void* d_out, int out_size, void* d_ws, size_t ws_size,
                              hipStream_t stream) {
    const float* x    = (const float*)d_in[0];
    const float* w    = (const float*)d_in[1];
    const float* bias = (const float*)d_in[2];
    const float* aw   = (const float*)d_in[3];
    const float* aA   = (const float*)d_in[4];

    const int    OUT = in_sizes[2];
    const size_t wsz = (size_t)in_sizes[1];
    const int    IN  = (int)(wsz / OUT);
    const int    M   = in_sizes[0] / IN;    // 8192
    const int    N   = OUT;                 // 4096
    const int    K   = IN;                  // 4096

    char* ws = (char*)d_ws;
    _Float16* qx = (_Float16*)ws;                                   // M*K*2
    _Float16* qw = (_Float16*)(ws + (size_t)M * K * 2);             // N*K*2
    float* afeat   = (float*)(ws + (size_t)M * K * 2 + (size_t)N * K * 2);
    float* partial = afeat + K;                                     // 32*K

    const int NCHUNK = 32;
    dim3 g1(K / 256, NCHUNK);
    colsum_partial_kernel<<<g1, 256, 0, stream>>>(aA, partial, K, OUT / NCHUNK);
    colsum_final_kernel<<<K / 256, 256, 0, stream>>>(partial, afeat, K, NCHUNK,
                                                     1.0f / (float)OUT);

    const size_t nx8 = (size_t)M * K / 8;
    const size_t nw8 = (size_t)N * K / 8;
    quant_xw8_kernel<<<2048, 256, 0, stream>>>(x, afeat, (f16x8*)qx,
                                               w, aw, (f16x8*)qw,
                                               K, nx8, nx8 + nw8);

    const int nwg = (M / 256) * (N / 256);
    gemm_p4_kernel<<<nwg, 512, 0, stream>>>(qx, qw, bias, (float*)d_out,
                                            M, N, K);
}

// Round 16
// 400.918 us; speedup vs baseline: 1.0062x; 1.0062x over previous
//
#include <hip/hip_runtime.h>
#include <hip/hip_fp16.h>
#include <cstdint>
#include <cstddef>

typedef _Float16 f16x8 __attribute__((ext_vector_type(8)));
typedef _Float16 f16x4 __attribute__((ext_vector_type(4)));
typedef float    f32x4 __attribute__((ext_vector_type(4)));

// ---------------------------------------------------------------------------
// fake-quant with fractional bit-width interpolation (matches jax reference)
// ---------------------------------------------------------------------------
__device__ __forceinline__ float quant_interp(float v, float alpha) {
    float a    = fmaxf(alpha, 1.0f);
    float blo  = floorf(a);
    float frac = a - blo;
    float slo  = exp2f(blo) - 1.0f;
    float shi  = 2.0f * slo + 1.0f;
    float rslo = __builtin_amdgcn_rcpf(slo);
    float rshi = __builtin_amdgcn_rcpf(shi);
    float c    = fminf(fmaxf(v, -1.0f), 1.0f);
    float qlo  = rintf(c * slo) * rslo;
    float qhi  = rintf(c * shi) * rshi;
    return (1.0f - frac) * qlo + frac * qhi;
}

// ---------------------------------------------------------------------------
// column mean of alpha_a [OUT][IN] -> a_feat [IN], deterministic two-pass
// ---------------------------------------------------------------------------
__global__ void colsum_partial_kernel(const float* __restrict__ aA,
                                      float* __restrict__ partial,
                                      int IN, int rows_per) {
    int col = blockIdx.x * blockDim.x + threadIdx.x;
    size_t r0 = (size_t)blockIdx.y * rows_per;
    float s = 0.f;
    for (int r = 0; r < rows_per; ++r)
        s += aA[(r0 + r) * (size_t)IN + col];
    partial[(size_t)blockIdx.y * IN + col] = s;
}

__global__ void colsum_final_kernel(const float* __restrict__ partial,
                                    float* __restrict__ afeat,
                                    int IN, int nchunk, float inv) {
    int col = blockIdx.x * blockDim.x + threadIdx.x;
    float s = 0.f;
    for (int c = 0; c < nchunk; ++c)
        s += partial[(size_t)c * IN + col];
    afeat[col] = s * inv;
}

// ---------------------------------------------------------------------------
// fused quantize (ONE launch): x then w, 32B loads / 16B store per iteration
// ---------------------------------------------------------------------------
__global__ void quant_xw8_kernel(const float* __restrict__ x,
                                 const float* __restrict__ afeat,
                                 f16x8* __restrict__ qx,
                                 const float* __restrict__ w,
                                 const float* __restrict__ aw,
                                 f16x8* __restrict__ qw,
                                 int IN, size_t nx8, size_t ntot8) {
    size_t i = (size_t)blockIdx.x * blockDim.x + threadIdx.x;
    size_t stride = (size_t)gridDim.x * blockDim.x;
    for (; i < ntot8; i += stride) {
        if (i < nx8) {
            size_t e = i * 8;
            int col = (int)(e % (size_t)IN);
            f32x4 x0 = *(const f32x4*)(x + e);
            f32x4 x1 = *(const f32x4*)(x + e + 4);
            f32x4 a0 = *(const f32x4*)(afeat + col);
            f32x4 a1 = *(const f32x4*)(afeat + col + 4);
            f16x8 o;
            #pragma unroll
            for (int j = 0; j < 4; ++j) o[j]     = (_Float16)quant_interp(x0[j], a0[j]);
            #pragma unroll
            for (int j = 0; j < 4; ++j) o[4 + j] = (_Float16)quant_interp(x1[j], a1[j]);
            qx[i] = o;
        } else {
            size_t k = (i - nx8) * 8;
            f32x4 w0 = *(const f32x4*)(w + k);
            f32x4 w1 = *(const f32x4*)(w + k + 4);
            f32x4 a0 = *(const f32x4*)(aw + k);
            f32x4 a1 = *(const f32x4*)(aw + k + 4);
            f16x8 o;
            #pragma unroll
            for (int j = 0; j < 4; ++j) o[j]     = (_Float16)quant_interp(w0[j], a0[j]);
            #pragma unroll
            for (int j = 0; j < 4; ++j) o[4 + j] = (_Float16)quant_interp(w1[j], a1[j]);
            qw[i - nx8] = o;
        }
    }
}

// ---------------------------------------------------------------------------
// 256x256 NT GEMM, fp16 in / fp32 out — depth-pipelined 4-buffer BK=32.
//   R15 measured 281us / MfmaUtil 43.8% / SQ_LDS_BANK_CONFLICT 2.5e7. The
//   conflicts (first nonzero all session) come from the swizzle slot =
//   hi^(row&3): bank-set = (row&1)*4 + (hi^(row&3)) repeats every 4 rows ->
//   r15 and r15+4 collide = 4-way conflict (~384 cyc/tile of the measured
//   2634). FIX: xr = (row>>1)&3. Then bank-set = (r15&1)*4+(hi^((r15>>1)&3))
//   enumerates all 8 bank-sets exactly once for r15=0..7 (uniform 2
//   lanes/bank = free). Applied on BOTH sides (rule #21): staging source
//   pre-XOR sg=(tid&3)^((row>>1)&3), read slot sl=hi^((row>>1)&3).
//   Schedule unchanged from R15 (re-audited):
//   Per K-tile t (bufs: read t&3, pre-read (t+1)&3, landing (t+2)&3,
//   writing (t+3)&3 — pairwise distinct):
//     af[8]  <- ds_read buf[t][A]                  (published 2 bars ago)
//     bfN[4] <- pre-read B(t+1) from buf[t+1][B]   (published 1 bar ago)
//     stage tile t+3 -> buf[t+3]                   (4 gload_lds)
//     32 MFMA on af x bfC (bfC pre-read LAST tile: zero lgkm wait at start)
//     vmcnt(4) [drains stage(t+2)]; lgkmcnt(0) [publication fence, AFTER
//     MFMAs]; s_barrier. ONE barrier/tile. Tail: stages skip -> gate 0.
// ---------------------------------------------------------------------------
__device__ __forceinline__ void gload_lds16(const void* g, void* l) {
    __builtin_amdgcn_global_load_lds(
        (const __attribute__((address_space(1))) void*)g,
        (__attribute__((address_space(3))) void*)l, 16, 0, 0);
}

__device__ __forceinline__ f16x8 lds_frag32(const _Float16* buf, int row, int hi) {
    const int sl = hi ^ ((row >> 1) & 3);
    return *(const f16x8*)((const char*)buf + row * 64 + sl * 16);
}

#define GATE(N)  asm volatile("s_waitcnt vmcnt(" N ")" ::: "memory")
#define LGKM0()  asm volatile("s_waitcnt lgkmcnt(0)" ::: "memory")
#define BAR()    asm volatile("s_barrier" ::: "memory")

#define READ_BN(T, DST)                                                      \
    if ((T) < nkt) {                                                         \
        const _Float16* Bn = &lds[(T) & 3][1][0];                            \
        _Pragma("unroll")                                                    \
        for (int nf = 0; nf < 4; ++nf)                                       \
            DST[nf] = lds_frag32(Bn, (nf >> 1) * 128 + wn * 32 +             \
                                     (nf & 1) * 16 + r15, hi);               \
    }

#define BODY(T, BFC, BFN)                                                    \
  {                                                                          \
    const _Float16* Ab = &lds[(T) & 3][0][0];                                \
    f16x8 af[8];                                                             \
    _Pragma("unroll")                                                        \
    for (int mf = 0; mf < 8; ++mf)                                           \
        af[mf] = lds_frag32(Ab, wm * 128 + mf * 16 + r15, hi);               \
    READ_BN((T) + 1, BFN);                                                   \
    STAGE32((T) + 3, 0); STAGE32((T) + 3, 1);                                \
    __builtin_amdgcn_s_setprio(1);                                           \
    _Pragma("unroll")                                                        \
    for (int mf = 0; mf < 8; ++mf)                                           \
        _Pragma("unroll")                                                    \
        for (int nf = 0; nf < 4; ++nf)                                       \
            acc[mf][nf] = __builtin_amdgcn_mfma_f32_16x16x32_f16(            \
                af[mf], BFC[nf], acc[mf][nf], 0, 0, 0);                      \
    __builtin_amdgcn_s_setprio(0);                                           \
    if ((T) < nkt - 3) { GATE("4"); } else { GATE("0"); }                    \
    LGKM0(); BAR();                                                          \
  }

__global__ __launch_bounds__(512, 2) void gemm_p4s_kernel(
    const _Float16* __restrict__ A,   // [M][K] qx
    const _Float16* __restrict__ B,   // [N][K] qw
    const float* __restrict__ bias,   // [N]
    float* __restrict__ C,            // [M][N]
    int M, int N, int K)
{
    constexpr int BK = 32;
    __shared__ _Float16 lds[4][2][256 * BK];   // 4 bufs x {A,B} x 16KB = 128K

    const int tid  = (int)threadIdx.x;
    const int lane = tid & 63;
    const int wave = tid >> 6;
    const int wm   = wave >> 2;    // 0..1  (M half: rows wm*128..+127)
    const int wn   = wave & 3;     // 0..3
    const int r15  = lane & 15;
    const int hi   = lane >> 4;

    const int nbx = N >> 8;
    const int nwg = (M >> 8) * nbx;
    const int bid = (int)blockIdx.x;
    const int swz = (nwg & 7) ? bid : ((bid & 7) * (nwg >> 3) + (bid >> 3));
    const size_t bm0 = (size_t)(swz / nbx) << 8;
    const size_t bn0 = (size_t)(swz % nbx) << 8;

    const int nkt = K / BK;
    const _Float16* Agb = A + bm0 * K;
    const _Float16* Bgb = B + bn0 * K;

    // stage one operand of a BK=32 tile (256 rows x 32 halfs = 16KB):
    // 2 gload_lds per thread; linear LDS dest (row = p*128 + (tid>>2),
    // byte = p*8192 + tid*16), source slot pre-XORed with (row>>1)&3.
    auto STAGE32 = [&](int tile, int ab) {
        if (tile >= nkt) return;
        const _Float16* g = (ab == 0 ? Agb : Bgb) + (size_t)tile * BK;
        char* lb = (char*)&lds[tile & 3][ab][0];
        #pragma unroll
        for (int p = 0; p < 2; ++p) {
            const int row = p * 128 + (tid >> 2);
            const int sg  = (tid & 3) ^ ((row >> 1) & 3);
            gload_lds16(g + (size_t)row * K + sg * 8,
                        lb + p * 8192 + (wave << 10));
        }
    };

    f32x4 acc[8][4] = {};
    f16x8 bfC[4], bfN[4];

    // prologue: stage tiles 0,1 (8 loads); full drain + publish; pre-read
    // B(0); stage tile 2 (queue=4 = steady invariant); fence; publish.
    STAGE32(0, 0); STAGE32(0, 1); STAGE32(1, 0); STAGE32(1, 1);
    GATE("0"); BAR();
    READ_BN(0, bfC);
    STAGE32(2, 0); STAGE32(2, 1);
    LGKM0(); BAR();

    for (int t = 0; t < nkt; t += 2) {
        BODY(t,     bfC, bfN);
        BODY(t + 1, bfN, bfC);
    }

    // epilogue: C/D layout col = lane&15, row = (lane>>4)*4 + reg
    #pragma unroll
    for (int nf = 0; nf < 4; ++nf) {
        const size_t col = bn0 + (size_t)((nf >> 1) * 128 + wn * 32 + (nf & 1) * 16 + r15);
        const float bv = bias[col];
        #pragma unroll
        for (int mf = 0; mf < 8; ++mf) {
            const size_t row0 = bm0 + (size_t)(wm * 128 + mf * 16 + hi * 4);
            #pragma unroll
            for (int r = 0; r < 4; ++r)
                C[(row0 + r) * N + col] = acc[mf][nf][r] + bv;
        }
    }
}

// ---------------------------------------------------------------------------
extern "C" void kernel_launch(void* const* d_in, const int* in_sizes, int n_in,
                              void* d_out, int out_size, void* d_ws, size_t ws_size,
                              hipStream_t stream) {
    const float* x    = (const float*)d_in[0];
    const float* w    = (const float*)d_in[1];
    const float* bias = (const float*)d_in[2];
    const float* aw   = (const float*)d_in[3];
    const float* aA   = (const float*)d_in[4];

    const int    OUT = in_sizes[2];
    const size_t wsz = (size_t)in_sizes[1];
    const int    IN  = (int)(wsz / OUT);
    const int    M   = in_sizes[0] / IN;    // 8192
    const int    N   = OUT;                 // 4096
    const int    K   = IN;                  // 4096

    char* ws = (char*)d_ws;
    _Float16* qx = (_Float16*)ws;                                   // M*K*2
    _Float16* qw = (_Float16*)(ws + (size_t)M * K * 2);             // N*K*2
    float* afeat   = (float*)(ws + (size_t)M * K * 2 + (size_t)N * K * 2);
    float* partial = afeat + K;                                     // 32*K

    const int NCHUNK = 32;
    dim3 g1(K / 256, NCHUNK);
    colsum_partial_kernel<<<g1, 256, 0, stream>>>(aA, partial, K, OUT / NCHUNK);
    colsum_final_kernel<<<K / 256, 256, 0, stream>>>(partial, afeat, K, NCHUNK,
                                                     1.0f / (float)OUT);

    const size_t nx8 = (size_t)M * K / 8;
    const size_t nw8 = (size_t)N * K / 8;
    quant_xw8_kernel<<<2048, 256, 0, stream>>>(x, afeat, (f16x8*)qx,
                                               w, aw, (f16x8*)qw,
                                               K, nx8, nx8 + nw8);

    const int nwg = (M / 256) * (N / 256);
    gemm_p4s_kernel<<<nwg, 512, 0, stream>>>(qx, qw, bias, (float*)d_out,
                                             M, N, K);
}

// Round 17
// 387.692 us; speedup vs baseline: 1.0406x; 1.0341x over previous
//
#include <hip/hip_runtime.h>
#include <hip/hip_fp16.h>
#include <cstdint>
#include <cstddef>

typedef _Float16 f16x8 __attribute__((ext_vector_type(8)));
typedef _Float16 f16x4 __attribute__((ext_vector_type(4)));
typedef float    f32x4 __attribute__((ext_vector_type(4)));

// ---------------------------------------------------------------------------
// fake-quant with fractional bit-width interpolation (matches jax reference)
// ---------------------------------------------------------------------------
__device__ __forceinline__ float quant_interp(float v, float alpha) {
    float a    = fmaxf(alpha, 1.0f);
    float blo  = floorf(a);
    float frac = a - blo;
    float slo  = exp2f(blo) - 1.0f;
    float shi  = 2.0f * slo + 1.0f;
    float rslo = __builtin_amdgcn_rcpf(slo);
    float rshi = __builtin_amdgcn_rcpf(shi);
    float c    = fminf(fmaxf(v, -1.0f), 1.0f);
    float qlo  = rintf(c * slo) * rslo;
    float qhi  = rintf(c * shi) * rshi;
    return (1.0f - frac) * qlo + frac * qhi;
}

// ---------------------------------------------------------------------------
// column mean of alpha_a [OUT][IN] -> a_feat [IN], deterministic two-pass,
// f32x4-vectorized (16B/lane loads & stores)
// ---------------------------------------------------------------------------
__global__ void colsum_partial4_kernel(const float* __restrict__ aA,
                                       float* __restrict__ partial,
                                       int IN, int rows_per) {
    int c4 = blockIdx.x * blockDim.x + threadIdx.x;   // f32x4 column group
    size_t r0 = (size_t)blockIdx.y * rows_per;
    f32x4 s = {0.f, 0.f, 0.f, 0.f};
    for (int r = 0; r < rows_per; ++r) {
        f32x4 v = *(const f32x4*)(aA + (r0 + r) * (size_t)IN + (size_t)c4 * 4);
        s += v;
    }
    *(f32x4*)(partial + (size_t)blockIdx.y * IN + (size_t)c4 * 4) = s;
}

__global__ void colsum_final4_kernel(const float* __restrict__ partial,
                                     float* __restrict__ afeat,
                                     int IN, int nchunk, float inv) {
    int c4 = blockIdx.x * blockDim.x + threadIdx.x;
    f32x4 s = {0.f, 0.f, 0.f, 0.f};
    for (int c = 0; c < nchunk; ++c)
        s += *(const f32x4*)(partial + (size_t)c * IN + (size_t)c4 * 4);
    *(f32x4*)(afeat + (size_t)c4 * 4) = s * inv;
}

// ---------------------------------------------------------------------------
// fused quantize (ONE launch, two branch-free grid-stride loops):
//   loop 1: x [M][IN] with per-column alpha -> qx (fp16)
//   loop 2: w [OUT][IN] with per-element alpha -> qw (fp16)
// 32B loads / 16B store per iteration.
// ---------------------------------------------------------------------------
__global__ void quant_xw8_kernel(const float* __restrict__ x,
                                 const float* __restrict__ afeat,
                                 f16x8* __restrict__ qx,
                                 const float* __restrict__ w,
                                 const float* __restrict__ aw,
                                 f16x8* __restrict__ qw,
                                 int IN, size_t nx8, size_t nw8) {
    const size_t t0 = (size_t)blockIdx.x * blockDim.x + threadIdx.x;
    const size_t stride = (size_t)gridDim.x * blockDim.x;

    for (size_t i = t0; i < nx8; i += stride) {
        size_t e = i * 8;
        int col = (int)(e % (size_t)IN);
        f32x4 x0 = *(const f32x4*)(x + e);
        f32x4 x1 = *(const f32x4*)(x + e + 4);
        f32x4 a0 = *(const f32x4*)(afeat + col);
        f32x4 a1 = *(const f32x4*)(afeat + col + 4);
        f16x8 o;
        #pragma unroll
        for (int j = 0; j < 4; ++j) o[j]     = (_Float16)quant_interp(x0[j], a0[j]);
        #pragma unroll
        for (int j = 0; j < 4; ++j) o[4 + j] = (_Float16)quant_interp(x1[j], a1[j]);
        qx[i] = o;
    }
    for (size_t i = t0; i < nw8; i += stride) {
        size_t k = i * 8;
        f32x4 w0 = *(const f32x4*)(w + k);
        f32x4 w1 = *(const f32x4*)(w + k + 4);
        f32x4 a0 = *(const f32x4*)(aw + k);
        f32x4 a1 = *(const f32x4*)(aw + k + 4);
        f16x8 o;
        #pragma unroll
        for (int j = 0; j < 4; ++j) o[j]     = (_Float16)quant_interp(w0[j], a0[j]);
        #pragma unroll
        for (int j = 0; j < 4; ++j) o[4 + j] = (_Float16)quant_interp(w1[j], a1[j]);
        qw[i] = o;
    }
}

// ---------------------------------------------------------------------------
// 256x256 NT GEMM, fp16 in / fp32 out — BYTE-EXACT R12 (best measured: 252us,
// MfmaUtil 50%, 0 bank conflicts). 2 phases/K-tile, no lockstep forcers:
// compiler emits counted lgkmcnt per MFMA dep; counted vmcnt gates (8,6)
// before each barrier; stages at distance 1/2; XOR slot swizzle with inverse
// on the GLOBAL source (rule #21). R7-R16's seven scheduling/data-path
// variants (A-direct x3, 4-phase lockstep, k-slice rotation, BK=32
// depth-pipeline x2) all regressed or tied -- this is the structure optimum
// for this template family on 1-block/CU occupancy.
// ---------------------------------------------------------------------------
__device__ __forceinline__ void gload_lds16(const void* g, void* l) {
    __builtin_amdgcn_global_load_lds(
        (const __attribute__((address_space(1))) void*)g,
        (__attribute__((address_space(3))) void*)l, 16, 0, 0);
}

__device__ __forceinline__ f16x8 lds_frag(const _Float16* buf, int row, int ks, int hi) {
    const int sl = (ks * 4 + hi) ^ (row & 7);
    return *(const f16x8*)((const char*)buf + row * 128 + sl * 16);
}

#define GATE(N)  asm volatile("s_waitcnt vmcnt(" N ")" ::: "memory")
#define BAR()    asm volatile("s_barrier" ::: "memory")

#define READ_A(BUF, MH)                                                      \
    _Pragma("unroll")                                                        \
    for (int mi = 0; mi < 4; ++mi) {                                         \
        const int row = (MH) * 128 + wm * 64 + mi * 16 + r15;                \
        af[mi][0] = lds_frag(BUF, row, 0, hi);                               \
        af[mi][1] = lds_frag(BUF, row, 1, hi);                               \
    }

#define READ_BF(BUF)                                                         \
    _Pragma("unroll")                                                        \
    for (int nf = 0; nf < 4; ++nf) {                                         \
        const int row = (nf >> 1) * 128 + wn * 32 + (nf & 1) * 16 + r15;     \
        bf[nf][0] = lds_frag(BUF, row, 0, hi);                               \
        bf[nf][1] = lds_frag(BUF, row, 1, hi);                               \
    }

#define MFMA32(MH)                                                           \
    __builtin_amdgcn_s_setprio(1);                                           \
    _Pragma("unroll")                                                        \
    for (int mi = 0; mi < 4; ++mi)                                           \
        _Pragma("unroll")                                                    \
        for (int nf = 0; nf < 4; ++nf) {                                     \
            f32x4& ac = acc[(MH) * 4 + mi][nf];                              \
            ac = __builtin_amdgcn_mfma_f32_16x16x32_f16(af[mi][0], bf[nf][0], ac, 0, 0, 0); \
            ac = __builtin_amdgcn_mfma_f32_16x16x32_f16(af[mi][1], bf[nf][1], ac, 0, 0, 0); \
        }                                                                    \
    __builtin_amdgcn_s_setprio(0);

// which: 0=A0 1=A1 2=B0 3=B1
#define TILE2(T, G0, G1)                                                     \
  {                                                                          \
    const _Float16* Ab = sA[(T) & 1];                                        \
    const _Float16* Bb = sB[(T) & 1];                                        \
    f16x8 af[4][2];                                                          \
    READ_A(Ab, 0);                                                           \
    READ_BF(Bb);                                                             \
    STAGE((T) + 1, 3); STAGE((T) + 1, 1);                                    \
    MFMA32(0);                                                               \
    GATE(G0); BAR();                                                         \
    READ_A(Ab, 1);                                                           \
    STAGE((T) + 2, 0); STAGE((T) + 2, 2);                                    \
    MFMA32(1);                                                               \
    GATE(G1); BAR();                                                         \
  }

__global__ __launch_bounds__(512, 2) void gemm2pf_kernel(
    const _Float16* __restrict__ A,   // [M][K] qx
    const _Float16* __restrict__ B,   // [N][K] qw
    const float* __restrict__ bias,   // [N]
    float* __restrict__ C,            // [M][N]
    int M, int N, int K)
{
    constexpr int BK = 64;
    __shared__ _Float16 sA[2][256 * BK];   // 64 KiB
    __shared__ _Float16 sB[2][256 * BK];   // 64 KiB

    const int tid  = (int)threadIdx.x;
    const int lane = tid & 63;
    const int wave = tid >> 6;
    const int wm   = wave >> 2;    // 0..1
    const int wn   = wave & 3;     // 0..3
    const int r15  = lane & 15;
    const int hi   = lane >> 4;

    const int nbx = N >> 8;
    const int nwg = (M >> 8) * nbx;
    const int bid = (int)blockIdx.x;
    const int swz = (nwg & 7) ? bid : ((bid & 7) * (nwg >> 3) + (bid >> 3));
    const size_t bm0 = (size_t)(swz / nbx) << 8;
    const size_t bn0 = (size_t)(swz % nbx) << 8;

    const int nkt = K / BK;
    const _Float16* Agb = A + bm0 * K;
    const _Float16* Bgb = B + bn0 * K;

    auto STAGE = [&](int tile, int which) {
        if (tile >= nkt) return;
        const _Float16* g = (which < 2 ? Agb : Bgb) + (size_t)tile * BK;
        _Float16* lb = (which < 2 ? sA[tile & 1] : sB[tile & 1]);
        const int rb = (which & 1) << 7;
        #pragma unroll
        for (int rr = 0; rr < 2; ++rr) {
            const int row = rb + rr * 64 + (tid >> 3);
            const int sg  = (tid & 7) ^ (row & 7);
            gload_lds16(g + (size_t)row * K + sg * 8,
                        (char*)lb + ((rb + rr * 64) << 7) + (wave << 10));
        }
    };

    f32x4 acc[8][4] = {};
    f16x8 bf[4][2];

    // prologue: A0(0),B0(0),B1(0),A1(0),A0(1),B0(1) = 12 loads;
    // vmcnt(6) drains tile0's A0,B0,B1; leaves [A1(0),A0(1),B0(1)] in flight
    STAGE(0, 0); STAGE(0, 2); STAGE(0, 3); STAGE(0, 1);
    STAGE(1, 0); STAGE(1, 2);
    GATE("6"); BAR();

    int t = 0;
    for (; t < nkt - 3; ++t)
        TILE2(t, "8", "6");
    for (; t < nkt; ++t)           // tail: stages skip -> full drain is safe
        TILE2(t, "0", "0");

    // epilogue: C/D layout col = lane&15, row = (lane>>4)*4 + reg
    #pragma unroll
    for (int nf = 0; nf < 4; ++nf) {
        const size_t col = bn0 + (size_t)((nf >> 1) * 128 + wn * 32 + (nf & 1) * 16 + r15);
        const float bv = bias[col];
        #pragma unroll
        for (int mf = 0; mf < 8; ++mf) {
            const size_t row0 = bm0 + (size_t)((mf >> 2) * 128 + wm * 64 + (mf & 3) * 16 + hi * 4);
            #pragma unroll
            for (int r = 0; r < 4; ++r)
                C[(row0 + r) * N + col] = acc[mf][nf][r] + bv;
        }
    }
}

// ---------------------------------------------------------------------------
extern "C" void kernel_launch(void* const* d_in, const int* in_sizes, int n_in,
                              void* d_out, int out_size, void* d_ws, size_t ws_size,
                              hipStream_t stream) {
    const float* x    = (const float*)d_in[0];
    const float* w    = (const float*)d_in[1];
    const float* bias = (const float*)d_in[2];
    const float* aw   = (const float*)d_in[3];
    const float* aA   = (const float*)d_in[4];

    const int    OUT = in_sizes[2];
    const size_t wsz = (size_t)in_sizes[1];
    const int    IN  = (int)(wsz / OUT);
    const int    M   = in_sizes[0] / IN;    // 8192
    const int    N   = OUT;                 // 4096
    const int    K   = IN;                  // 4096

    char* ws = (char*)d_ws;
    _Float16* qx = (_Float16*)ws;                                   // M*K*2
    _Float16* qw = (_Float16*)(ws + (size_t)M * K * 2);             // N*K*2
    float* afeat   = (float*)(ws + (size_t)M * K * 2 + (size_t)N * K * 2);
    float* partial = afeat + K;                                     // 32*K

    const int NCHUNK = 32;
    dim3 g1(K / 1024, NCHUNK);                 // f32x4 per thread
    colsum_partial4_kernel<<<g1, 256, 0, stream>>>(aA, partial, K, OUT / NCHUNK);
    colsum_final4_kernel<<<K / 1024, 256, 0, stream>>>(partial, afeat, K, NCHUNK,
                                                       1.0f / (float)OUT);

    const size_t nx8 = (size_t)M * K / 8;
    const size_t nw8 = (size_t)N * K / 8;
    quant_xw8_kernel<<<2048, 256, 0, stream>>>(x, afeat, (f16x8*)qx,
                                               w, aw, (f16x8*)qw,
                                               K, nx8, nw8);

    const int nwg = (M / 256) * (N / 256);
    gemm2pf_kernel<<<nwg, 512, 0, stream>>>(qx, qw, bias, (float*)d_out,
                                            M, N, K);
}

// Round 18
// 366.917 us; speedup vs baseline: 1.0995x; 1.0566x over previous
//
#include <hip/hip_runtime.h>
#include <hip/hip_fp16.h>
#include <cstdint>
#include <cstddef>

typedef _Float16 f16x8 __attribute__((ext_vector_type(8)));
typedef _Float16 f16x4 __attribute__((ext_vector_type(4)));
typedef float    f32x4 __attribute__((ext_vector_type(4)));

// ---------------------------------------------------------------------------
// fake-quant with fractional bit-width interpolation (matches jax reference)
// ---------------------------------------------------------------------------
__device__ __forceinline__ float quant_interp(float v, float alpha) {
    float a    = fmaxf(alpha, 1.0f);
    float blo  = floorf(a);
    float frac = a - blo;
    float slo  = exp2f(blo) - 1.0f;
    float shi  = 2.0f * slo + 1.0f;
    float rslo = __builtin_amdgcn_rcpf(slo);
    float rshi = __builtin_amdgcn_rcpf(shi);
    float c    = fminf(fmaxf(v, -1.0f), 1.0f);
    float qlo  = rintf(c * slo) * rslo;
    float qhi  = rintf(c * shi) * rshi;
    return (1.0f - frac) * qlo + frac * qhi;
}

// ---------------------------------------------------------------------------
// column mean of alpha_a [OUT][IN] -> a_feat [IN], deterministic two-pass,
// f32x4-vectorized. NCHUNK=64 -> 256 blocks (all CUs busy; R17's 128 blocks
// left half the chip idle => ~20us for a ~10us read).
// ---------------------------------------------------------------------------
__global__ void colsum_partial4_kernel(const float* __restrict__ aA,
                                       float* __restrict__ partial,
                                       int IN, int rows_per) {
    int c4 = blockIdx.x * blockDim.x + threadIdx.x;   // f32x4 column group
    size_t r0 = (size_t)blockIdx.y * rows_per;
    f32x4 s = {0.f, 0.f, 0.f, 0.f};
    for (int r = 0; r < rows_per; ++r) {
        f32x4 v = *(const f32x4*)(aA + (r0 + r) * (size_t)IN + (size_t)c4 * 4);
        s += v;
    }
    *(f32x4*)(partial + (size_t)blockIdx.y * IN + (size_t)c4 * 4) = s;
}

__global__ void colsum_final4_kernel(const float* __restrict__ partial,
                                     float* __restrict__ afeat,
                                     int IN, int nchunk, float inv) {
    int c4 = blockIdx.x * blockDim.x + threadIdx.x;
    f32x4 s = {0.f, 0.f, 0.f, 0.f};
    for (int c = 0; c < nchunk; ++c)
        s += *(const f32x4*)(partial + (size_t)c * IN + (size_t)c4 * 4);
    *(f32x4*)(afeat + (size_t)c4 * 4) = s * inv;
}

// ---------------------------------------------------------------------------
// fused quantize (ONE launch):
//   x-loop: per-column alpha. When stride*8 % IN == 0 (true for our launch
//   config), each thread's 8 columns are INVARIANT across iterations ->
//   hoist all alpha-derived params (floor/exp2/rcp x2 -- the quarter-rate
//   transcendentals) to ONE computation per thread; the loop body is pure
//   full-rate clamp/rint/mul. Generic fallback kept for correctness.
//   w-loop: per-element alpha (irreducible), unchanged.
// Exact same per-element formula as R12 -> absmax unchanged (0.03125).
// ---------------------------------------------------------------------------
__global__ void quant_xw8_kernel(const float* __restrict__ x,
                                 const float* __restrict__ afeat,
                                 f16x8* __restrict__ qx,
                                 const float* __restrict__ w,
                                 const float* __restrict__ aw,
                                 f16x8* __restrict__ qw,
                                 int IN, size_t nx8, size_t nw8) {
    const size_t t0 = (size_t)blockIdx.x * blockDim.x + threadIdx.x;
    const size_t stride = (size_t)gridDim.x * blockDim.x;

    if (((stride * 8) % (size_t)IN) == 0) {
        // hoisted path: thread's column block is fixed
        const int col = (int)((t0 * 8) % (size_t)IN);
        f32x4 a0 = *(const f32x4*)(afeat + col);
        f32x4 a1 = *(const f32x4*)(afeat + col + 4);
        f32x4 fr0, sl0, rl0, sh0, rh0, fr1, sl1, rl1, sh1, rh1;
        #pragma unroll
        for (int j = 0; j < 4; ++j) {
            float a = fmaxf(a0[j], 1.0f); float b = floorf(a);
            fr0[j] = a - b; sl0[j] = exp2f(b) - 1.0f; sh0[j] = 2.0f * sl0[j] + 1.0f;
            rl0[j] = __builtin_amdgcn_rcpf(sl0[j]);
            rh0[j] = __builtin_amdgcn_rcpf(sh0[j]);
            a = fmaxf(a1[j], 1.0f); b = floorf(a);
            fr1[j] = a - b; sl1[j] = exp2f(b) - 1.0f; sh1[j] = 2.0f * sl1[j] + 1.0f;
            rl1[j] = __builtin_amdgcn_rcpf(sl1[j]);
            rh1[j] = __builtin_amdgcn_rcpf(sh1[j]);
        }
        for (size_t i = t0; i < nx8; i += stride) {
            size_t e = i * 8;
            f32x4 x0 = *(const f32x4*)(x + e);
            f32x4 x1 = *(const f32x4*)(x + e + 4);
            f16x8 o;
            #pragma unroll
            for (int j = 0; j < 4; ++j) {
                float c = fminf(fmaxf(x0[j], -1.0f), 1.0f);
                float qlo = rintf(c * sl0[j]) * rl0[j];
                float qhi = rintf(c * sh0[j]) * rh0[j];
                o[j] = (_Float16)((1.0f - fr0[j]) * qlo + fr0[j] * qhi);
            }
            #pragma unroll
            for (int j = 0; j < 4; ++j) {
                float c = fminf(fmaxf(x1[j], -1.0f), 1.0f);
                float qlo = rintf(c * sl1[j]) * rl1[j];
                float qhi = rintf(c * sh1[j]) * rh1[j];
                o[4 + j] = (_Float16)((1.0f - fr1[j]) * qlo + fr1[j] * qhi);
            }
            qx[i] = o;
        }
    } else {
        for (size_t i = t0; i < nx8; i += stride) {
            size_t e = i * 8;
            int col = (int)(e % (size_t)IN);
            f32x4 x0 = *(const f32x4*)(x + e);
            f32x4 x1 = *(const f32x4*)(x + e + 4);
            f32x4 a0 = *(const f32x4*)(afeat + col);
            f32x4 a1 = *(const f32x4*)(afeat + col + 4);
            f16x8 o;
            #pragma unroll
            for (int j = 0; j < 4; ++j) o[j]     = (_Float16)quant_interp(x0[j], a0[j]);
            #pragma unroll
            for (int j = 0; j < 4; ++j) o[4 + j] = (_Float16)quant_interp(x1[j], a1[j]);
            qx[i] = o;
        }
    }

    for (size_t i = t0; i < nw8; i += stride) {
        size_t k = i * 8;
        f32x4 w0 = *(const f32x4*)(w + k);
        f32x4 w1 = *(const f32x4*)(w + k + 4);
        f32x4 a0 = *(const f32x4*)(aw + k);
        f32x4 a1 = *(const f32x4*)(aw + k + 4);
        f16x8 o;
        #pragma unroll
        for (int j = 0; j < 4; ++j) o[j]     = (_Float16)quant_interp(w0[j], a0[j]);
        #pragma unroll
        for (int j = 0; j < 4; ++j) o[4 + j] = (_Float16)quant_interp(w1[j], a1[j]);
        qw[i] = o;
    }
}

// ---------------------------------------------------------------------------
// 256x256 NT GEMM, fp16 in / fp32 out — BYTE-EXACT R12 (best measured: 250us,
// MfmaUtil 49.5%, 0 bank conflicts). 2 phases/K-tile, no lockstep forcers:
// compiler emits counted lgkmcnt per MFMA dep; counted vmcnt gates (8,6)
// before each barrier; stages at distance 1/2; XOR slot swizzle with inverse
// on the GLOBAL source (rule #21). Seven schedule/data-path variants
// (A-direct x3, 4-phase lockstep, k-slice rotation, BK=32 depth-pipeline x2)
// all regressed or tied — frozen.
// ---------------------------------------------------------------------------
__device__ __forceinline__ void gload_lds16(const void* g, void* l) {
    __builtin_amdgcn_global_load_lds(
        (const __attribute__((address_space(1))) void*)g,
        (__attribute__((address_space(3))) void*)l, 16, 0, 0);
}

__device__ __forceinline__ f16x8 lds_frag(const _Float16* buf, int row, int ks, int hi) {
    const int sl = (ks * 4 + hi) ^ (row & 7);
    return *(const f16x8*)((const char*)buf + row * 128 + sl * 16);
}

#define GATE(N)  asm volatile("s_waitcnt vmcnt(" N ")" ::: "memory")
#define BAR()    asm volatile("s_barrier" ::: "memory")

#define READ_A(BUF, MH)                                                      \
    _Pragma("unroll")                                                        \
    for (int mi = 0; mi < 4; ++mi) {                                         \
        const int row = (MH) * 128 + wm * 64 + mi * 16 + r15;                \
        af[mi][0] = lds_frag(BUF, row, 0, hi);                               \
        af[mi][1] = lds_frag(BUF, row, 1, hi);                               \
    }

#define READ_BF(BUF)                                                         \
    _Pragma("unroll")                                                        \
    for (int nf = 0; nf < 4; ++nf) {                                         \
        const int row = (nf >> 1) * 128 + wn * 32 + (nf & 1) * 16 + r15;     \
        bf[nf][0] = lds_frag(BUF, row, 0, hi);                               \
        bf[nf][1] = lds_frag(BUF, row, 1, hi);                               \
    }

#define MFMA32(MH)                                                           \
    __builtin_amdgcn_s_setprio(1);                                           \
    _Pragma("unroll")                                                        \
    for (int mi = 0; mi < 4; ++mi)                                           \
        _Pragma("unroll")                                                    \
        for (int nf = 0; nf < 4; ++nf) {                                     \
            f32x4& ac = acc[(MH) * 4 + mi][nf];                              \
            ac = __builtin_amdgcn_mfma_f32_16x16x32_f16(af[mi][0], bf[nf][0], ac, 0, 0, 0); \
            ac = __builtin_amdgcn_mfma_f32_16x16x32_f16(af[mi][1], bf[nf][1], ac, 0, 0, 0); \
        }                                                                    \
    __builtin_amdgcn_s_setprio(0);

// which: 0=A0 1=A1 2=B0 3=B1
#define TILE2(T, G0, G1)                                                     \
  {                                                                          \
    const _Float16* Ab = sA[(T) & 1];                                        \
    const _Float16* Bb = sB[(T) & 1];                                        \
    f16x8 af[4][2];                                                          \
    READ_A(Ab, 0);                                                           \
    READ_BF(Bb);                                                             \
    STAGE((T) + 1, 3); STAGE((T) + 1, 1);                                    \
    MFMA32(0);                                                               \
    GATE(G0); BAR();                                                         \
    READ_A(Ab, 1);                                                           \
    STAGE((T) + 2, 0); STAGE((T) + 2, 2);                                    \
    MFMA32(1);                                                               \
    GATE(G1); BAR();                                                         \
  }

__global__ __launch_bounds__(512, 2) void gemm2pf_kernel(
    const _Float16* __restrict__ A,   // [M][K] qx
    const _Float16* __restrict__ B,   // [N][K] qw
    const float* __restrict__ bias,   // [N]
    float* __restrict__ C,            // [M][N]
    int M, int N, int K)
{
    constexpr int BK = 64;
    __shared__ _Float16 sA[2][256 * BK];   // 64 KiB
    __shared__ _Float16 sB[2][256 * BK];   // 64 KiB

    const int tid  = (int)threadIdx.x;
    const int lane = tid & 63;
    const int wave = tid >> 6;
    const int wm   = wave >> 2;    // 0..1
    const int wn   = wave & 3;     // 0..3
    const int r15  = lane & 15;
    const int hi   = lane >> 4;

    const int nbx = N >> 8;
    const int nwg = (M >> 8) * nbx;
    const int bid = (int)blockIdx.x;
    const int swz = (nwg & 7) ? bid : ((bid & 7) * (nwg >> 3) + (bid >> 3));
    const size_t bm0 = (size_t)(swz / nbx) << 8;
    const size_t bn0 = (size_t)(swz % nbx) << 8;

    const int nkt = K / BK;
    const _Float16* Agb = A + bm0 * K;
    const _Float16* Bgb = B + bn0 * K;

    auto STAGE = [&](int tile, int which) {
        if (tile >= nkt) return;
        const _Float16* g = (which < 2 ? Agb : Bgb) + (size_t)tile * BK;
        _Float16* lb = (which < 2 ? sA[tile & 1] : sB[tile & 1]);
        const int rb = (which & 1) << 7;
        #pragma unroll
        for (int rr = 0; rr < 2; ++rr) {
            const int row = rb + rr * 64 + (tid >> 3);
            const int sg  = (tid & 7) ^ (row & 7);
            gload_lds16(g + (size_t)row * K + sg * 8,
                        (char*)lb + ((rb + rr * 64) << 7) + (wave << 10));
        }
    };

    f32x4 acc[8][4] = {};
    f16x8 bf[4][2];

    // prologue: A0(0),B0(0),B1(0),A1(0),A0(1),B0(1) = 12 loads;
    // vmcnt(6) drains tile0's A0,B0,B1; leaves [A1(0),A0(1),B0(1)] in flight
    STAGE(0, 0); STAGE(0, 2); STAGE(0, 3); STAGE(0, 1);
    STAGE(1, 0); STAGE(1, 2);
    GATE("6"); BAR();

    int t = 0;
    for (; t < nkt - 3; ++t)
        TILE2(t, "8", "6");
    for (; t < nkt; ++t)           // tail: stages skip -> full drain is safe
        TILE2(t, "0", "0");

    // epilogue: C/D layout col = lane&15, row = (lane>>4)*4 + reg
    #pragma unroll
    for (int nf = 0; nf < 4; ++nf) {
        const size_t col = bn0 + (size_t)((nf >> 1) * 128 + wn * 32 + (nf & 1) * 16 + r15);
        const float bv = bias[col];
        #pragma unroll
        for (int mf = 0; mf < 8; ++mf) {
            const size_t row0 = bm0 + (size_t)((mf >> 2) * 128 + wm * 64 + (mf & 3) * 16 + hi * 4);
            #pragma unroll
            for (int r = 0; r < 4; ++r)
                C[(row0 + r) * N + col] = acc[mf][nf][r] + bv;
        }
    }
}

// ---------------------------------------------------------------------------
extern "C" void kernel_launch(void* const* d_in, const int* in_sizes, int n_in,
                              void* d_out, int out_size, void* d_ws, size_t ws_size,
                              hipStream_t stream) {
    const float* x    = (const float*)d_in[0];
    const float* w    = (const float*)d_in[1];
    const float* bias = (const float*)d_in[2];
    const float* aw   = (const float*)d_in[3];
    const float* aA   = (const float*)d_in[4];

    const int    OUT = in_sizes[2];
    const size_t wsz = (size_t)in_sizes[1];
    const int    IN  = (int)(wsz / OUT);
    const int    M   = in_sizes[0] / IN;    // 8192
    const int    N   = OUT;                 // 4096
    const int    K   = IN;                  // 4096

    char* ws = (char*)d_ws;
    _Float16* qx = (_Float16*)ws;                                   // M*K*2
    _Float16* qw = (_Float16*)(ws + (size_t)M * K * 2);             // N*K*2
    float* afeat   = (float*)(ws + (size_t)M * K * 2 + (size_t)N * K * 2);
    float* partial = afeat + K;                                     // 64*K

    const int NCHUNK = 64;
    dim3 g1(K / 1024, NCHUNK);                 // f32x4 per thread, 256 blocks
    colsum_partial4_kernel<<<g1, 256, 0, stream>>>(aA, partial, K, OUT / NCHUNK);
    colsum_final4_kernel<<<K / 1024, 256, 0, stream>>>(partial, afeat, K, NCHUNK,
                                                       1.0f / (float)OUT);

    const size_t nx8 = (size_t)M * K / 8;
    const size_t nw8 = (size_t)N * K / 8;
    quant_xw8_kernel<<<2048, 256, 0, stream>>>(x, afeat, (f16x8*)qx,
                                               w, aw, (f16x8*)qw,
                                               K, nx8, nw8);

    const int nwg = (M / 256) * (N / 256);
    gemm2pf_kernel<<<nwg, 512, 0, stream>>>(qx, qw, bias, (float*)d_out,
                                            M, N, K);
}